// Round 2
// baseline (1655.667 us; speedup 1.0000x reference)
//
#include <hip/hip_runtime.h>
#include <stdint.h>
#include <math.h>

// Problem constants (fixed by setup_inputs)
#define H_IMG 256
#define W_IMG 128
#define LTOK  32768
#define BATCH 4
#define CDIM  256
#define HIDDIM 1024
#define NHEAD 8
#define HD    32
#define MROWS 131072   // B * L

typedef __attribute__((ext_vector_type(8))) short short8;
typedef __attribute__((ext_vector_type(4))) float f32x4;

// ---------- helpers ----------
__device__ __forceinline__ float bf2f(unsigned u) {
  union { unsigned u; float f; } c; c.u = u << 16; return c.f;
}
__device__ __forceinline__ unsigned short f2bf(float f) {
  union { float f; unsigned u; } c; c.f = f;
  unsigned r = c.u + 0x7fffu + ((c.u >> 16) & 1u);  // RNE
  return (unsigned short)(r >> 16);
}
__device__ __forceinline__ float gelu_f(float x) {
  return 0.5f * x * (1.0f + erff(x * 0.70710678118654752f));
}
__device__ __forceinline__ void gload_lds16(const void* g, void* l) {
  __builtin_amdgcn_global_load_lds(
      (const __attribute__((address_space(1))) unsigned int*)g,
      (__attribute__((address_space(3))) unsigned int*)l, 16, 0, 0);
}

// ---------- weight convert: f32 [K,N] -> bf16 [N,K] (transpose) ----------
__global__ __launch_bounds__(256) void wconv_kernel(
    const float* __restrict__ w, unsigned short* __restrict__ wt, int K, int N) {
  __shared__ float t[32][33];
  const int k0 = blockIdx.x * 32, n0 = blockIdx.y * 32;
  const int tx = threadIdx.x & 31, ty = threadIdx.x >> 5;
#pragma unroll
  for (int i = 0; i < 4; ++i)
    t[ty + 8 * i][tx] = w[(size_t)(k0 + ty + 8 * i) * N + n0 + tx];
  __syncthreads();
#pragma unroll
  for (int i = 0; i < 4; ++i)
    wt[(size_t)(n0 + ty + 8 * i) * K + k0 + tx] = f2bf(t[tx][ty + 8 * i]);
}

// ---------- LayerNorm (fp32 in -> bf16 out), one wave per row of C=256 ----------
__global__ __launch_bounds__(256) void ln_kernel(
    const float* __restrict__ x, const float* __restrict__ g,
    const float* __restrict__ b, unsigned short* __restrict__ out) {
  const int wave = threadIdx.x >> 6;
  const int lane = threadIdx.x & 63;
  const size_t row = (size_t)blockIdx.x * 4 + wave;
  float4 f = ((const float4*)(x + row * CDIM))[lane];
  float s  = f.x + f.y + f.z + f.w;
  float sq = f.x*f.x + f.y*f.y + f.z*f.z + f.w*f.w;
#pragma unroll
  for (int o = 32; o > 0; o >>= 1) { s += __shfl_down(s, o); sq += __shfl_down(sq, o); }
  s = __shfl(s, 0); sq = __shfl(sq, 0);
  const float mu = s * (1.0f / CDIM);
  const float var = sq * (1.0f / CDIM) - mu * mu;
  const float rstd = rsqrtf(var + 1e-5f);
  float4 gg = ((const float4*)g)[lane];
  float4 bb = ((const float4*)b)[lane];
  unsigned short o4[4];
  o4[0] = f2bf((f.x - mu) * rstd * gg.x + bb.x);
  o4[1] = f2bf((f.y - mu) * rstd * gg.y + bb.y);
  o4[2] = f2bf((f.z - mu) * rstd * gg.z + bb.z);
  o4[3] = f2bf((f.w - mu) * rstd * gg.w + bb.w);
  *(uint2*)(out + row * CDIM + lane * 4) = *(uint2*)o4;
}

// ---------- MFMA GEMM: out[M,:] = A[M,K](bf16) @ Bt[N,K](bf16)^T + bias ----------
// 2-phase double-buffered k-loop: STAGE(t+1) issued before compute(t), raw
// s_barrier + counted vmcnt(4) so next tile's HBM latency hides under MFMA.
// EPI 0: bf16 = acc+bias   EPI 1: f32 = acc+bias+res   EPI 2: bf16 = gelu(acc+bias)
// PERM 0: out idx = m*ldc+n
// PERM 1: q-perm  [b][win][head][tok64][32]  (roll+window gather on write)
// PERM 2: v-perm  [b][win][head][32][tok64]  (transposed within head)
// PERM 3: m is a permuted row (window-token-major); un-permute to token order.
template<int EPI, int PERM>
__global__ __launch_bounds__(256) void mgemm(
    const unsigned short* __restrict__ A, const unsigned short* __restrict__ Bt,
    const float* __restrict__ bias, float bscale, const float* __restrict__ res,
    void* __restrict__ outp, int K, int ldc,
    const int* __restrict__ pHo, const int* __restrict__ pWo) {
  __shared__ unsigned short As[2][128][32];
  __shared__ unsigned short Bs[2][128][32];
  const int tid = threadIdx.x;
  const int w = tid >> 6, lane = tid & 63;
  const int m0 = blockIdx.x * 128, n0 = blockIdx.y * 128;
  const int wm = (w & 1) * 64, wn = (w >> 1) * 64;
  const int srow = lane >> 2;                 // 0..15 within a 16-row chunk
  const int csrc = (lane & 3) ^ (srow & 3);   // swizzled source 16B-chunk
  f32x4 acc[4][4];
#pragma unroll
  for (int mi = 0; mi < 4; ++mi)
#pragma unroll
    for (int ni = 0; ni < 4; ++ni)
#pragma unroll
      for (int r = 0; r < 4; ++r) acc[mi][ni][r] = 0.0f;

  const int kg = lane >> 4, ml = lane & 15;
  const int nt = K >> 5;

  auto STAGE = [&](int kk, int buf) {
#pragma unroll
    for (int i = 0; i < 2; ++i) {
      const int rl = w * 32 + i * 16 + srow;       // local row 0..127
      gload_lds16(A + (size_t)(m0 + rl) * K + kk + csrc * 8, &As[buf][w * 32 + i * 16][0]);
      gload_lds16(Bt + (size_t)(n0 + rl) * K + kk + csrc * 8, &Bs[buf][w * 32 + i * 16][0]);
    }
  };

  STAGE(0, 0);
  for (int t = 0; t < nt; ++t) {
    const int cur = t & 1;
    if (t + 1 < nt) {
      STAGE((t + 1) << 5, cur ^ 1);
      asm volatile("s_waitcnt vmcnt(4)" ::: "memory");
    } else {
      asm volatile("s_waitcnt vmcnt(0)" ::: "memory");
    }
    __builtin_amdgcn_s_barrier();
    __builtin_amdgcn_sched_barrier(0);
    short8 af[4], bg[4];
#pragma unroll
    for (int mi = 0; mi < 4; ++mi) {
      const int r = wm + mi * 16 + ml;
      af[mi] = *(const short8*)&As[cur][r][(kg ^ (r & 3)) * 8];
    }
#pragma unroll
    for (int ni = 0; ni < 4; ++ni) {
      const int r = wn + ni * 16 + ml;
      bg[ni] = *(const short8*)&Bs[cur][r][(kg ^ (r & 3)) * 8];
    }
#pragma unroll
    for (int mi = 0; mi < 4; ++mi)
#pragma unroll
      for (int ni = 0; ni < 4; ++ni)
        acc[mi][ni] = __builtin_amdgcn_mfma_f32_16x16x32_bf16(af[mi], bg[ni], acc[mi][ni], 0, 0, 0);
    __builtin_amdgcn_sched_barrier(0);
    __builtin_amdgcn_s_barrier();
  }

  // epilogue: C/D layout col=lane&15, row=(lane>>4)*4+r
  const int Ho = (PERM == 1 || PERM == 2 || PERM == 3) ? pHo[0] : 0;
  const int Wo = (PERM == 1 || PERM == 2 || PERM == 3) ? pWo[0] : 0;
  size_t ridx[4][4];
#pragma unroll
  for (int mi = 0; mi < 4; ++mi) {
#pragma unroll
    for (int r = 0; r < 4; ++r) {
      const int m = m0 + wm + mi * 16 + kg * 4 + r;
      if constexpr (PERM == 1 || PERM == 2) {
        const int bimg = m >> 15, l = m & 32767;
        const int hq = l >> 7, wq_ = l & 127;
        int hr = hq - Ho; if (hr < 0) hr += H_IMG;
        int wr = wq_ - Wo; if (wr < 0) wr += W_IMG;
        const int win = (hr >> 3) * 16 + (wr >> 3);
        const int t64 = (hr & 7) * 8 + (wr & 7);
        ridx[mi][r] = (size_t)(bimg * 512 + win) * 16384 +
                      (PERM == 1 ? t64 * 32 : t64);
      } else if constexpr (PERM == 3) {
        const int bimg = m >> 15, win = (m >> 6) & 511, t64 = m & 63;
        int h = (win >> 4) * 8 + (t64 >> 3) + Ho; if (h >= H_IMG) h -= H_IMG;
        int ww_ = (win & 15) * 8 + (t64 & 7) + Wo; if (ww_ >= W_IMG) ww_ -= W_IMG;
        ridx[mi][r] = ((size_t)(bimg << 15) + h * W_IMG + ww_) * ldc;
      } else {
        ridx[mi][r] = (size_t)m * ldc;
      }
    }
  }
#pragma unroll
  for (int ni = 0; ni < 4; ++ni) {
    const int n = n0 + wn + ni * 16 + ml;
    const float bn = bias[n] * bscale;
    size_t noff;
    if constexpr (PERM == 1)      noff = (size_t)(n >> 5) * 2048 + (n & 31);
    else if constexpr (PERM == 2) noff = (size_t)(n >> 5) * 2048 + (n & 31) * 64;
    else                          noff = (size_t)n;
#pragma unroll
    for (int mi = 0; mi < 4; ++mi) {
#pragma unroll
      for (int r = 0; r < 4; ++r) {
        const size_t idx = ridx[mi][r] + noff;
        float val = acc[mi][ni][r] + bn;
        if (EPI == 1) {
          ((float*)outp)[idx] = val + res[idx];
        } else if (EPI == 2) {
          ((unsigned short*)outp)[idx] = f2bf(gelu_f(val));
        } else {
          ((unsigned short*)outp)[idx] = f2bf(val);
        }
      }
    }
  }
}

// ---------- Window attention via MFMA (k = q shared), permuted layouts ----------
// q: [b][512 win][8 head][64 tok][32]  -> Q/K fragments load direct from global
// v: [b][512 win][8 head][32 d][64 tok] -> V B-fragments load direct from global
// One block = one window (4 waves); wave w does heads {w, w+4}.
// Max-free softmax (scores bounded; mask -100 underflows in expf); 1/sum folded
// into O after PV. P round-trips through 8KB/wave LDS (swizzled, 4-way max).
// No __syncthreads in the hot loop; all LDS traffic wave-private.
__global__ __launch_bounds__(256, 3) void attn_kernel(
    const unsigned short* __restrict__ q, const unsigned short* __restrict__ v,
    const float* __restrict__ rpb, const int* __restrict__ pHo,
    const int* __restrict__ pWo, unsigned short* __restrict__ yout) {
  __shared__ unsigned short Pb[4][4096];   // per-wave P [64][64] (Ost overlays)
  __shared__ float bias_w[4][228];
  __shared__ int reg_s[64];
  const int tid = threadIdx.x;
  const int w = tid >> 6, lane = tid & 63;
  const int g = lane >> 4, c = lane & 15;
  const int wb = blockIdx.x;         // b*512 + wh*16 + ww
  const int b = wb >> 9, wloc = wb & 511;
  const int wh = wloc >> 4, ww = wloc & 15;
  const int Ho = pHo[0], Wo = pWo[0];
  const bool edge = (wh == (H_IMG / 8 - 1)) || (ww == (W_IMG / 8 - 1));
  if (w == 0) {
    const int dy = lane >> 3, dx = lane & 7;
    const int hr = wh * 8 + dy, wr = ww * 8 + dx;
    const int rh = (hr < H_IMG - 8) ? 0 : ((hr < H_IMG - Ho) ? 1 : 2);
    const int rw = (wr < W_IMG - 8) ? 0 : ((wr < W_IMG - Wo) ? 1 : 2);
    reg_s[lane] = rh * 3 + rw;
  }
  __syncthreads();

  const float scale = 0.17677669529663687f;  // 32^-0.5
  const int dxk = c & 7, dyk0 = c >> 3;
  const int base_l = 112 - dyk0 * 15 - dxk;  // rel = Aq + base_l - 30*nj
  const size_t hbase0 = (size_t)(b * 512 + wloc) * 8;

  for (int p2 = 0; p2 < 2; ++p2) {
    const int hh = w + 4 * p2;
    const unsigned short* qh = q + (hbase0 + hh) * 2048;
    const unsigned short* vh = v + (hbase0 + hh) * 2048;
    // bias slice (wave-private)
#pragma unroll
    for (int i = 0; i < 4; ++i) {
      const int idx = lane + 64 * i;
      if (idx < 225) bias_w[w][idx] = rpb[idx * 8 + hh];
    }
    // ---- fragments direct from global (fully coalesced 16B/lane) ----
    short8 q4[4];
#pragma unroll
    for (int mi = 0; mi < 4; ++mi)
      q4[mi] = *(const short8*)(qh + (16 * mi + c) * 32 + g * 8);
    short8 vf[2][2];
#pragma unroll
    for (int s2 = 0; s2 < 2; ++s2)
#pragma unroll
      for (int n2 = 0; n2 < 2; ++n2)
        vf[s2][n2] = *(const short8*)(vh + (16 * n2 + c) * 64 + 32 * s2 + 8 * g);
    // ---- QK^T: S[q-tile mi][k-tile nj] (same fragments serve A and B) ----
    f32x4 acc[4][4];
#pragma unroll
    for (int mi = 0; mi < 4; ++mi)
#pragma unroll
      for (int nj = 0; nj < 4; ++nj)
#pragma unroll
        for (int r = 0; r < 4; ++r) acc[mi][nj][r] = 0.0f;
#pragma unroll
    for (int mi = 0; mi < 4; ++mi)
#pragma unroll
      for (int nj = 0; nj < 4; ++nj)
        acc[mi][nj] = __builtin_amdgcn_mfma_f32_16x16x32_bf16(q4[mi], q4[nj], acc[mi][nj], 0, 0, 0);
    int regk[4];
    if (edge) {
#pragma unroll
      for (int nj = 0; nj < 4; ++nj) regk[nj] = reg_s[16 * nj + c];
    }
    // ---- max-free softmax per row (C-layout row q=16mi+4g+r, col kt=16nj+c) ----
    unsigned short* Pp = &Pb[w][0];
    float ivr[4][4];
#pragma unroll
    for (int mi = 0; mi < 4; ++mi) {
#pragma unroll
      for (int r = 0; r < 4; ++r) {
        const int qq = 16 * mi + 4 * g + r;
        const int rb = (qq >> 3) * 15 + (qq & 7) + base_l;
        float sv[4];
#pragma unroll
        for (int nj = 0; nj < 4; ++nj)
          sv[nj] = acc[mi][nj][r] * scale + bias_w[w][rb - 30 * nj];
        if (edge) {
          const int regq = reg_s[qq];
#pragma unroll
          for (int nj = 0; nj < 4; ++nj)
            if (regq != regk[nj]) sv[nj] -= 100.0f;
        }
        float e0 = __expf(sv[0]), e1 = __expf(sv[1]);
        float e2 = __expf(sv[2]), e3 = __expf(sv[3]);
        float sm = e0 + e1 + e2 + e3;
        sm += __shfl_xor(sm, 1);
        sm += __shfl_xor(sm, 2);
        sm += __shfl_xor(sm, 4);
        sm += __shfl_xor(sm, 8);
        ivr[mi][r] = __builtin_amdgcn_rcpf(sm);
        const int rowoff = qq * 64, sw = qq & 7;
        Pp[rowoff + ((dyk0 ^ sw) * 8)       + dxk] = f2bf(e0);
        Pp[rowoff + (((2 + dyk0) ^ sw) * 8) + dxk] = f2bf(e1);
        Pp[rowoff + (((4 + dyk0) ^ sw) * 8) + dxk] = f2bf(e2);
        Pp[rowoff + (((6 + dyk0) ^ sw) * 8) + dxk] = f2bf(e3);
      }
    }
    // ---- PV: O[q-tile mi][d-tile n2] over 2 K-steps ----
    f32x4 oacc[4][2];
#pragma unroll
    for (int mi = 0; mi < 4; ++mi)
#pragma unroll
      for (int n2 = 0; n2 < 2; ++n2)
#pragma unroll
        for (int r = 0; r < 4; ++r) oacc[mi][n2][r] = 0.0f;
#pragma unroll
    for (int s2 = 0; s2 < 2; ++s2) {
      short8 pa[4];
#pragma unroll
      for (int mi = 0; mi < 4; ++mi) {
        const int qq2 = 16 * mi + c;
        pa[mi] = *(const short8*)&Pp[qq2 * 64 + (((4 * s2 + g) ^ (qq2 & 7)) * 8)];
      }
#pragma unroll
      for (int mi = 0; mi < 4; ++mi)
#pragma unroll
        for (int n2 = 0; n2 < 2; ++n2)
          oacc[mi][n2] = __builtin_amdgcn_mfma_f32_16x16x32_bf16(pa[mi], vf[s2][n2], oacc[mi][n2], 0, 0, 0);
    }
    // ---- epilogue: normalize by 1/sum, restage O [64][40], coalesced write ----
    unsigned short* Ost = Pp;
#pragma unroll
    for (int mi = 0; mi < 4; ++mi)
#pragma unroll
      for (int n2 = 0; n2 < 2; ++n2)
#pragma unroll
        for (int r = 0; r < 4; ++r)
          Ost[(16 * mi + 4 * g + r) * 40 + 16 * n2 + c] = f2bf(oacc[mi][n2][r] * ivr[mi][r]);
    uint4* op = (uint4*)(yout + ((size_t)(b * 512 + wloc) * 64 + lane) * 256 + hh * 32);
#pragma unroll
    for (int u = 0; u < 4; ++u)
      op[u] = *(const uint4*)&Ost[lane * 40 + u * 8];
  }
}

// ---------- Depthwise 3x3 conv on a row band (full 1024 ch) + GELU ----------
__global__ __launch_bounds__(256) void dwconv_kernel(
    const unsigned short* __restrict__ t1b, const float* __restrict__ k9,
    const float* __restrict__ bias, unsigned short* __restrict__ t2b,
    int hr0, int band_rows) {
  const int c = blockIdx.y * 128 + (threadIdx.x & 31) * 4;
  const int tok = blockIdx.x * 8 + (threadIdx.x >> 5);   // 0..band_rows*128-1
  const int h = hr0 + (tok >> 7), wcol = tok & 127;
  float wreg[4][9];
#pragma unroll
  for (int j = 0; j < 4; ++j)
#pragma unroll
    for (int tp = 0; tp < 9; ++tp) wreg[j][tp] = k9[(c + j) * 9 + tp];
  const float4 bv = *(const float4*)(bias + c);
  float a0 = 0, a1 = 0, a2 = 0, a3 = 0;
#pragma unroll
  for (int ky = 0; ky < 3; ++ky) {
    const int hy = h + ky - 1;
    if ((unsigned)hy >= (unsigned)H_IMG) continue;
    const int brow = (tok >> 7) + ky;   // buffer row
#pragma unroll
    for (int kx = 0; kx < 3; ++kx) {
      const int wx = wcol + kx - 1;
      if ((unsigned)wx >= (unsigned)W_IMG) continue;
      const ushort4 tv = *(const ushort4*)(
          t1b + ((size_t)(brow * 128 + wx)) * HIDDIM + c);
      const int tp = ky * 3 + kx;
      a0 += bf2f(tv.x) * wreg[0][tp];
      a1 += bf2f(tv.y) * wreg[1][tp];
      a2 += bf2f(tv.z) * wreg[2][tp];
      a3 += bf2f(tv.w) * wreg[3][tp];
    }
  }
  a0 = gelu_f(a0 + bv.x); a1 = gelu_f(a1 + bv.y);
  a2 = gelu_f(a2 + bv.z); a3 = gelu_f(a3 + bv.w);
  unsigned short o[4] = { f2bf(a0), f2bf(a1), f2bf(a2), f2bf(a3) };
  *(uint2*)(t2b + (size_t)tok * HIDDIM + c) = *(uint2*)o;
}

// ---------- launch ----------
extern "C" void kernel_launch(void* const* d_in, const int* in_sizes, int n_in,
                              void* d_out, int out_size, void* d_ws, size_t ws_size,
                              hipStream_t stream) {
  (void)in_sizes; (void)n_in; (void)out_size; (void)ws_size;
  const float* x     = (const float*)d_in[0];
  const float* n1g   = (const float*)d_in[1];
  const float* n1b   = (const float*)d_in[2];
  const float* wq    = (const float*)d_in[3];
  const float* bq    = (const float*)d_in[4];
  const float* wv    = (const float*)d_in[5];
  const float* bv    = (const float*)d_in[6];
  const float* rpb   = (const float*)d_in[7];
  const float* wproj = (const float*)d_in[8];
  const float* bproj = (const float*)d_in[9];
  const float* n2g   = (const float*)d_in[10];
  const float* n2b   = (const float*)d_in[11];
  const float* w1    = (const float*)d_in[12];
  const float* b1    = (const float*)d_in[13];
  const float* dwk   = (const float*)d_in[14];
  const float* dwb   = (const float*)d_in[15];
  const float* w2    = (const float*)d_in[16];
  const float* b2    = (const float*)d_in[17];
  const int*   pHo   = (const int*)d_in[18];
  const int*   pWo   = (const int*)d_in[19];
  float* out = (float*)d_out;

  char* wsb = (char*)d_ws;
  unsigned short* r0     = (unsigned short*)wsb;
  unsigned short* wqt    = (unsigned short*)(wsb + 67108864ull);
  unsigned short* wvt    = (unsigned short*)(wsb + 67108864ull + 131072ull);
  unsigned short* wprojt = (unsigned short*)(wsb + 67108864ull + 262144ull);
  unsigned short* w1t    = (unsigned short*)(wsb + 67108864ull + 393216ull);
  unsigned short* w2t    = (unsigned short*)(wsb + 67108864ull + 917504ull);
  unsigned short* t1b    = (unsigned short*)(wsb + 68550656ull);
  unsigned short* t2b    = (unsigned short*)(wsb + 68550656ull + 25690112ull);
  unsigned short* vb     = (unsigned short*)d_out;
  unsigned short* qb     = (unsigned short*)((char*)d_out + 67108864ull);

  // 0. weight convert + transpose (f32 [K,N] -> bf16 [N,K])
  wconv_kernel<<<dim3(8, 8),  256, 0, stream>>>(wq,    wqt,    CDIM, CDIM);
  wconv_kernel<<<dim3(8, 8),  256, 0, stream>>>(wv,    wvt,    CDIM, CDIM);
  wconv_kernel<<<dim3(8, 8),  256, 0, stream>>>(wproj, wprojt, CDIM, CDIM);
  wconv_kernel<<<dim3(8, 32), 256, 0, stream>>>(w1,    w1t,    CDIM, HIDDIM);
  wconv_kernel<<<dim3(32, 8), 256, 0, stream>>>(w2,    w2t,    HIDDIM, CDIM);

  // 1. LN1: x -> xn (r0)
  ln_kernel<<<32768, 256, 0, stream>>>(x, n1g, n1b, r0);
  // 2-3. q,v projections -> permuted window-major layouts in d_out halves
  mgemm<0, 1><<<dim3(1024, 2), 256, 0, stream>>>(r0, wqt, bq, 1.0f, nullptr, qb, CDIM, CDIM, pHo, pWo);
  mgemm<0, 2><<<dim3(1024, 2), 256, 0, stream>>>(r0, wvt, bv, 1.0f, nullptr, vb, CDIM, CDIM, pHo, pWo);
  // 4. window attention (k = q) -> yattn (r0, window-token-major)
  attn_kernel<<<dim3(2048), 256, 0, stream>>>(qb, vb, rpb, pHo, pWo, r0);
  // 5. xattn = x + yattn@wproj + bproj -> d_out f32 (un-permute rows on write)
  mgemm<1, 3><<<dim3(1024, 2), 256, 0, stream>>>(r0, wprojt, bproj, 1.0f, x, out, CDIM, CDIM, pHo, pWo);
  // 6. LN2: d_out -> xn2 (r0)
  ln_kernel<<<32768, 256, 0, stream>>>(out, n2g, n2b, r0);
  // 7-9. LeFF over row bands
  for (int bi = 0; bi < BATCH; ++bi) {
    for (int hr0 = 0; hr0 < H_IMG; ) {
      const int br = (H_IMG - hr0 >= 96) ? 96 : (H_IMG - hr0);
      const int r_start = (hr0 > 0) ? hr0 - 1 : 0;
      const int r_end = (hr0 + br <= H_IMG - 1) ? hr0 + br : H_IMG - 1;
      const int nrows = r_end - r_start + 1;
      const unsigned short* Aff1 = r0 + ((size_t)bi * LTOK + (size_t)r_start * W_IMG) * CDIM;
      unsigned short* t1dst = t1b + (size_t)(r_start - hr0 + 1) * W_IMG * HIDDIM;
      mgemm<2, 0><<<dim3(nrows, 8), 256, 0, stream>>>(
          Aff1, w1t, b1, 1.0f, nullptr, t1dst, CDIM, HIDDIM, pHo, pWo);
      dwconv_kernel<<<dim3(br * 16, 8), 256, 0, stream>>>(t1b, dwk, dwb, t2b, hr0, br);
      const size_t btok = (size_t)bi * LTOK + (size_t)hr0 * W_IMG;
      mgemm<1, 0><<<dim3(br, 2), 256, 0, stream>>>(
          t2b, w2t, b2, 1.0f, out + btok * CDIM, out + btok * CDIM, HIDDIM, CDIM, pHo, pWo);
      hr0 += br;
    }
  }
}

// Round 3
// 1643.682 us; speedup vs baseline: 1.0073x; 1.0073x over previous
//
#include <hip/hip_runtime.h>
#include <stdint.h>
#include <math.h>

// Problem constants (fixed by setup_inputs)
#define H_IMG 256
#define W_IMG 128
#define LTOK  32768
#define BATCH 4
#define CDIM  256
#define HIDDIM 1024
#define NHEAD 8
#define HD    32
#define MROWS 131072   // B * L

typedef __attribute__((ext_vector_type(8))) short short8;
typedef __attribute__((ext_vector_type(4))) float f32x4;

// ---------- helpers ----------
__device__ __forceinline__ float bf2f(unsigned u) {
  union { unsigned u; float f; } c; c.u = u << 16; return c.f;
}
__device__ __forceinline__ unsigned short f2bf(float f) {
  union { float f; unsigned u; } c; c.f = f;
  unsigned r = c.u + 0x7fffu + ((c.u >> 16) & 1u);  // RNE
  return (unsigned short)(r >> 16);
}
__device__ __forceinline__ void unpack8(uint4 t, float* dst) {
  dst[0] = bf2f(t.x & 0xffffu); dst[1] = bf2f(t.x >> 16);
  dst[2] = bf2f(t.y & 0xffffu); dst[3] = bf2f(t.y >> 16);
  dst[4] = bf2f(t.z & 0xffffu); dst[5] = bf2f(t.z >> 16);
  dst[6] = bf2f(t.w & 0xffffu); dst[7] = bf2f(t.w >> 16);
}
__device__ __forceinline__ float gelu_f(float x) {
  return 0.5f * x * (1.0f + erff(x * 0.70710678118654752f));
}
__device__ __forceinline__ void gload_lds16(const void* g, void* l) {
  __builtin_amdgcn_global_load_lds(
      (const __attribute__((address_space(1))) unsigned int*)g,
      (__attribute__((address_space(3))) unsigned int*)l, 16, 0, 0);
}

// ---------- weight convert: f32 [K,N] -> bf16 [N,K] (transpose) ----------
__global__ __launch_bounds__(256) void wconv_kernel(
    const float* __restrict__ w, unsigned short* __restrict__ wt, int K, int N) {
  __shared__ float t[32][33];
  const int k0 = blockIdx.x * 32, n0 = blockIdx.y * 32;
  const int tx = threadIdx.x & 31, ty = threadIdx.x >> 5;
#pragma unroll
  for (int i = 0; i < 4; ++i)
    t[ty + 8 * i][tx] = w[(size_t)(k0 + ty + 8 * i) * N + n0 + tx];
  __syncthreads();
#pragma unroll
  for (int i = 0; i < 4; ++i)
    wt[(size_t)(n0 + ty + 8 * i) * K + k0 + tx] = f2bf(t[tx][ty + 8 * i]);
}

// ---------- LayerNorm (fp32 in -> bf16 out), one wave per row of C=256 ----------
__global__ __launch_bounds__(256) void ln_kernel(
    const float* __restrict__ x, const float* __restrict__ g,
    const float* __restrict__ b, unsigned short* __restrict__ out) {
  const int wave = threadIdx.x >> 6;
  const int lane = threadIdx.x & 63;
  const size_t row = (size_t)blockIdx.x * 4 + wave;
  float4 f = ((const float4*)(x + row * CDIM))[lane];
  float s  = f.x + f.y + f.z + f.w;
  float sq = f.x*f.x + f.y*f.y + f.z*f.z + f.w*f.w;
#pragma unroll
  for (int o = 32; o > 0; o >>= 1) { s += __shfl_down(s, o); sq += __shfl_down(sq, o); }
  s = __shfl(s, 0); sq = __shfl(sq, 0);
  const float mu = s * (1.0f / CDIM);
  const float var = sq * (1.0f / CDIM) - mu * mu;
  const float rstd = rsqrtf(var + 1e-5f);
  float4 gg = ((const float4*)g)[lane];
  float4 bb = ((const float4*)b)[lane];
  unsigned short o4[4];
  o4[0] = f2bf((f.x - mu) * rstd * gg.x + bb.x);
  o4[1] = f2bf((f.y - mu) * rstd * gg.y + bb.y);
  o4[2] = f2bf((f.z - mu) * rstd * gg.z + bb.z);
  o4[3] = f2bf((f.w - mu) * rstd * gg.w + bb.w);
  *(uint2*)(out + row * CDIM + lane * 4) = *(uint2*)o4;
}

// ---------- MFMA GEMM: out[M,:] = A[M,K](bf16) @ Bt[N,K](bf16)^T + bias ----------
// 2-phase double-buffered k-loop: STAGE(t+1) issued before compute(t), raw
// s_barrier + counted vmcnt(4) so next tile's HBM latency hides under MFMA.
// EPI 0: bf16 = acc+bias   EPI 1: f32 = acc+bias+res   EPI 2: bf16 = gelu(acc+bias)
// PERM 0: linear, out idx = m*ldc+n
// PERM 4: fused q/v projection. Bt has 512 rows ([wq cols; wv cols]); the
//   n0<256 half writes q-perm [b][win][head][tok64][32] to outp, the n0>=256
//   half writes v-perm [b][win][head][32][tok64] to outp2 (roll+window gather
//   folded into the write addresses).
template<int EPI, int PERM>
__global__ __launch_bounds__(256) void mgemm(
    const unsigned short* __restrict__ A, const unsigned short* __restrict__ Bt,
    const float* __restrict__ bias, const float* __restrict__ bias2,
    const float* __restrict__ res, void* __restrict__ outp, void* __restrict__ outp2,
    int K, int ldc, const int* __restrict__ pHo, const int* __restrict__ pWo) {
  __shared__ unsigned short As[2][128][32];
  __shared__ unsigned short Bs[2][128][32];
  const int tid = threadIdx.x;
  const int w = tid >> 6, lane = tid & 63;
  const int m0 = blockIdx.x * 128, n0 = blockIdx.y * 128;
  const int wm = (w & 1) * 64, wn = (w >> 1) * 64;
  const int srow = lane >> 2;                 // 0..15 within a 16-row chunk
  const int csrc = (lane & 3) ^ (srow & 3);   // swizzled source 16B-chunk
  f32x4 acc[4][4];
#pragma unroll
  for (int mi = 0; mi < 4; ++mi)
#pragma unroll
    for (int ni = 0; ni < 4; ++ni)
#pragma unroll
      for (int r = 0; r < 4; ++r) acc[mi][ni][r] = 0.0f;

  const int kg = lane >> 4, ml = lane & 15;
  const int nt = K >> 5;

  auto STAGE = [&](int kk, int buf) {
#pragma unroll
    for (int i = 0; i < 2; ++i) {
      const int rl = w * 32 + i * 16 + srow;       // local row 0..127
      gload_lds16(A + (size_t)(m0 + rl) * K + kk + csrc * 8, &As[buf][w * 32 + i * 16][0]);
      gload_lds16(Bt + (size_t)(n0 + rl) * K + kk + csrc * 8, &Bs[buf][w * 32 + i * 16][0]);
    }
  };

  STAGE(0, 0);
  for (int t = 0; t < nt; ++t) {
    const int cur = t & 1;
    if (t + 1 < nt) {
      STAGE((t + 1) << 5, cur ^ 1);
      asm volatile("s_waitcnt vmcnt(4)" ::: "memory");
    } else {
      asm volatile("s_waitcnt vmcnt(0)" ::: "memory");
    }
    __builtin_amdgcn_s_barrier();
    __builtin_amdgcn_sched_barrier(0);
    short8 af[4], bg[4];
#pragma unroll
    for (int mi = 0; mi < 4; ++mi) {
      const int r = wm + mi * 16 + ml;
      af[mi] = *(const short8*)&As[cur][r][(kg ^ (r & 3)) * 8];
    }
#pragma unroll
    for (int ni = 0; ni < 4; ++ni) {
      const int r = wn + ni * 16 + ml;
      bg[ni] = *(const short8*)&Bs[cur][r][(kg ^ (r & 3)) * 8];
    }
#pragma unroll
    for (int mi = 0; mi < 4; ++mi)
#pragma unroll
      for (int ni = 0; ni < 4; ++ni)
        acc[mi][ni] = __builtin_amdgcn_mfma_f32_16x16x32_bf16(af[mi], bg[ni], acc[mi][ni], 0, 0, 0);
    __builtin_amdgcn_sched_barrier(0);
    __builtin_amdgcn_s_barrier();
  }

  // epilogue: C/D layout col=lane&15, row=(lane>>4)*4+r
  if constexpr (PERM == 4) {
    const int Ho = pHo[0], Wo = pWo[0];
    const bool vhalf = (n0 >= 256);
    size_t rbase[4][4];
#pragma unroll
    for (int mi = 0; mi < 4; ++mi) {
#pragma unroll
      for (int r = 0; r < 4; ++r) {
        const int m = m0 + wm + mi * 16 + kg * 4 + r;
        const int bimg = m >> 15, l = m & 32767;
        int hr = (l >> 7) - Ho; if (hr < 0) hr += H_IMG;
        int wr = (l & 127) - Wo; if (wr < 0) wr += W_IMG;
        const int win = (hr >> 3) * 16 + (wr >> 3);
        const int t64 = (hr & 7) * 8 + (wr & 7);
        rbase[mi][r] = (size_t)(bimg * 512 + win) * 16384 + (vhalf ? t64 : t64 * 32);
      }
    }
    unsigned short* dst = (unsigned short*)(vhalf ? outp2 : outp);
    const float* bp = vhalf ? bias2 : bias;
#pragma unroll
    for (int ni = 0; ni < 4; ++ni) {
      const int nn = n0 + wn + ni * 16 + ml - (vhalf ? 256 : 0);
      const float bn = bp[nn];
      const size_t noff = (size_t)(nn >> 5) * 2048 + (vhalf ? (nn & 31) * 64 : (nn & 31));
#pragma unroll
      for (int mi = 0; mi < 4; ++mi)
#pragma unroll
        for (int r = 0; r < 4; ++r)
          dst[rbase[mi][r] + noff] = f2bf(acc[mi][ni][r] + bn);
    }
  } else {
#pragma unroll
    for (int ni = 0; ni < 4; ++ni) {
      const int n = n0 + wn + ni * 16 + ml;
      const float bn = bias[n];
#pragma unroll
      for (int mi = 0; mi < 4; ++mi) {
#pragma unroll
        for (int r = 0; r < 4; ++r) {
          const int m = m0 + wm + mi * 16 + kg * 4 + r;
          const size_t idx = (size_t)m * ldc + n;
          float val = acc[mi][ni][r] + bn;
          if (EPI == 1) {
            ((float*)outp)[idx] = val + res[idx];
          } else if (EPI == 2) {
            ((unsigned short*)outp)[idx] = f2bf(gelu_f(val));
          } else {
            ((unsigned short*)outp)[idx] = f2bf(val);
          }
        }
      }
    }
  }
}

// ---------- Window attention via MFMA (k = q shared), permuted inputs ----------
// q: [b][512 win][8 head][64 tok][32]  -> Q/K fragments load direct from global
// v: [b][512 win][8 head][32 d][64 tok] -> V B-fragments load direct from global
// OUTPUT is written at un-permuted TOKEN addresses (roll folded in) so the
// following wproj GEMM is fully linear. One block = one window (4 waves);
// wave w does heads {w, w+4}. Max-free softmax (scores bounded; mask -100
// underflows in expf); 1/sum folded into O after PV. P round-trips through
// 4KB/wave LDS (swizzled). No __syncthreads in the hot loop.
__global__ __launch_bounds__(256, 3) void attn_kernel(
    const unsigned short* __restrict__ q, const unsigned short* __restrict__ v,
    const float* __restrict__ rpb, const int* __restrict__ pHo,
    const int* __restrict__ pWo, unsigned short* __restrict__ yout) {
  __shared__ unsigned short Pb[4][4096];   // per-wave P [64][64] (Ost overlays)
  __shared__ float bias_w[4][228];
  __shared__ int reg_s[64];
  const int tid = threadIdx.x;
  const int w = tid >> 6, lane = tid & 63;
  const int g = lane >> 4, c = lane & 15;
  const int wb = blockIdx.x;         // b*512 + wh*16 + ww
  const int b = wb >> 9, wloc = wb & 511;
  const int wh = wloc >> 4, ww = wloc & 15;
  const int Ho = pHo[0], Wo = pWo[0];
  const bool edge = (wh == (H_IMG / 8 - 1)) || (ww == (W_IMG / 8 - 1));
  if (w == 0) {
    const int dy = lane >> 3, dx = lane & 7;
    const int hr = wh * 8 + dy, wr = ww * 8 + dx;
    const int rh = (hr < H_IMG - 8) ? 0 : ((hr < H_IMG - Ho) ? 1 : 2);
    const int rw = (wr < W_IMG - 8) ? 0 : ((wr < W_IMG - Wo) ? 1 : 2);
    reg_s[lane] = rh * 3 + rw;
  }
  __syncthreads();

  const float scale = 0.17677669529663687f;  // 32^-0.5
  const int dxk = c & 7, dyk0 = c >> 3;
  const int base_l = 112 - dyk0 * 15 - dxk;  // rel = Aq + base_l - 30*nj
  const size_t hbase0 = (size_t)(b * 512 + wloc) * 8;
  // un-permuted token address for this lane's output row
  const int dy2 = lane >> 3, dx2 = lane & 7;
  int h2 = wh * 8 + dy2 + Ho; if (h2 >= H_IMG) h2 -= H_IMG;
  int w2_ = ww * 8 + dx2 + Wo; if (w2_ >= W_IMG) w2_ -= W_IMG;
  const size_t otok = (size_t)b * LTOK + (size_t)h2 * W_IMG + w2_;

  for (int p2 = 0; p2 < 2; ++p2) {
    const int hh = w + 4 * p2;
    const unsigned short* qh = q + (hbase0 + hh) * 2048;
    const unsigned short* vh = v + (hbase0 + hh) * 2048;
    // bias slice (wave-private)
#pragma unroll
    for (int i = 0; i < 4; ++i) {
      const int idx = lane + 64 * i;
      if (idx < 225) bias_w[w][idx] = rpb[idx * 8 + hh];
    }
    // ---- fragments direct from global (fully coalesced 16B/lane) ----
    short8 q4[4];
#pragma unroll
    for (int mi = 0; mi < 4; ++mi)
      q4[mi] = *(const short8*)(qh + (16 * mi + c) * 32 + g * 8);
    short8 vf[2][2];
#pragma unroll
    for (int s2 = 0; s2 < 2; ++s2)
#pragma unroll
      for (int n2 = 0; n2 < 2; ++n2)
        vf[s2][n2] = *(const short8*)(vh + (16 * n2 + c) * 64 + 32 * s2 + 8 * g);
    // ---- QK^T: S[q-tile mi][k-tile nj] (same fragments serve A and B) ----
    f32x4 acc[4][4];
#pragma unroll
    for (int mi = 0; mi < 4; ++mi)
#pragma unroll
      for (int nj = 0; nj < 4; ++nj)
#pragma unroll
        for (int r = 0; r < 4; ++r) acc[mi][nj][r] = 0.0f;
#pragma unroll
    for (int mi = 0; mi < 4; ++mi)
#pragma unroll
      for (int nj = 0; nj < 4; ++nj)
        acc[mi][nj] = __builtin_amdgcn_mfma_f32_16x16x32_bf16(q4[mi], q4[nj], acc[mi][nj], 0, 0, 0);
    int regk[4];
    if (edge) {
#pragma unroll
      for (int nj = 0; nj < 4; ++nj) regk[nj] = reg_s[16 * nj + c];
    }
    // ---- max-free softmax per row (C-layout row q=16mi+4g+r, col kt=16nj+c) ----
    unsigned short* Pp = &Pb[w][0];
    float ivr[4][4];
#pragma unroll
    for (int mi = 0; mi < 4; ++mi) {
#pragma unroll
      for (int r = 0; r < 4; ++r) {
        const int qq = 16 * mi + 4 * g + r;
        const int rb = (qq >> 3) * 15 + (qq & 7) + base_l;
        float sv[4];
#pragma unroll
        for (int nj = 0; nj < 4; ++nj)
          sv[nj] = acc[mi][nj][r] * scale + bias_w[w][rb - 30 * nj];
        if (edge) {
          const int regq = reg_s[qq];
#pragma unroll
          for (int nj = 0; nj < 4; ++nj)
            if (regq != regk[nj]) sv[nj] -= 100.0f;
        }
        float e0 = __expf(sv[0]), e1 = __expf(sv[1]);
        float e2 = __expf(sv[2]), e3 = __expf(sv[3]);
        float sm = e0 + e1 + e2 + e3;
        sm += __shfl_xor(sm, 1);
        sm += __shfl_xor(sm, 2);
        sm += __shfl_xor(sm, 4);
        sm += __shfl_xor(sm, 8);
        ivr[mi][r] = __builtin_amdgcn_rcpf(sm);
        const int rowoff = qq * 64, sw = qq & 7;
        Pp[rowoff + ((dyk0 ^ sw) * 8)       + dxk] = f2bf(e0);
        Pp[rowoff + (((2 + dyk0) ^ sw) * 8) + dxk] = f2bf(e1);
        Pp[rowoff + (((4 + dyk0) ^ sw) * 8) + dxk] = f2bf(e2);
        Pp[rowoff + (((6 + dyk0) ^ sw) * 8) + dxk] = f2bf(e3);
      }
    }
    // ---- PV: O[q-tile mi][d-tile n2] over 2 K-steps ----
    f32x4 oacc[4][2];
#pragma unroll
    for (int mi = 0; mi < 4; ++mi)
#pragma unroll
      for (int n2 = 0; n2 < 2; ++n2)
#pragma unroll
        for (int r = 0; r < 4; ++r) oacc[mi][n2][r] = 0.0f;
#pragma unroll
    for (int s2 = 0; s2 < 2; ++s2) {
      short8 pa[4];
#pragma unroll
      for (int mi = 0; mi < 4; ++mi) {
        const int qq2 = 16 * mi + c;
        pa[mi] = *(const short8*)&Pp[qq2 * 64 + (((4 * s2 + g) ^ (qq2 & 7)) * 8)];
      }
#pragma unroll
      for (int mi = 0; mi < 4; ++mi)
#pragma unroll
        for (int n2 = 0; n2 < 2; ++n2)
          oacc[mi][n2] = __builtin_amdgcn_mfma_f32_16x16x32_bf16(pa[mi], vf[s2][n2], oacc[mi][n2], 0, 0, 0);
    }
    // ---- epilogue: normalize by 1/sum, restage O [64][40], coalesced write ----
    unsigned short* Ost = Pp;
#pragma unroll
    for (int mi = 0; mi < 4; ++mi)
#pragma unroll
      for (int n2 = 0; n2 < 2; ++n2)
#pragma unroll
        for (int r = 0; r < 4; ++r)
          Ost[(16 * mi + 4 * g + r) * 40 + 16 * n2 + c] = f2bf(oacc[mi][n2][r] * ivr[mi][r]);
    uint4* op = (uint4*)(yout + otok * CDIM + hh * 32);
#pragma unroll
    for (int u = 0; u < 4; ++u)
      op[u] = *(const uint4*)&Ost[lane * 40 + u * 8];
  }
}

// ---------- Depthwise 3x3 conv on a row band (full 1024 ch) + GELU ----------
// 8 channels/thread (uint4 loads, 16B stores).
__global__ __launch_bounds__(256) void dwconv_kernel(
    const unsigned short* __restrict__ t1b, const float* __restrict__ k9,
    const float* __restrict__ bias, unsigned short* __restrict__ t2b,
    int hr0, int band_rows) {
  const int c = blockIdx.y * 256 + (threadIdx.x & 31) * 8;
  const int tok = blockIdx.x * 8 + (threadIdx.x >> 5);   // 0..band_rows*128-1
  const int h = hr0 + (tok >> 7), wcol = tok & 127;
  float wreg[8][9];
#pragma unroll
  for (int j = 0; j < 8; ++j)
#pragma unroll
    for (int tp = 0; tp < 9; ++tp) wreg[j][tp] = k9[(c + j) * 9 + tp];
  float bb[8];
#pragma unroll
  for (int j = 0; j < 8; ++j) bb[j] = bias[c + j];
  float a[8] = {};
#pragma unroll
  for (int ky = 0; ky < 3; ++ky) {
    const int hy = h + ky - 1;
    if ((unsigned)hy >= (unsigned)H_IMG) continue;
    const int brow = (tok >> 7) + ky;   // buffer row
#pragma unroll
    for (int kx = 0; kx < 3; ++kx) {
      const int wx = wcol + kx - 1;
      if ((unsigned)wx >= (unsigned)W_IMG) continue;
      const uint4 tv = *(const uint4*)(
          t1b + ((size_t)(brow * 128 + wx)) * HIDDIM + c);
      float f8[8];
      unpack8(tv, f8);
      const int tp = ky * 3 + kx;
#pragma unroll
      for (int j = 0; j < 8; ++j) a[j] += f8[j] * wreg[j][tp];
    }
  }
  unsigned short o[8];
#pragma unroll
  for (int j = 0; j < 8; ++j) o[j] = f2bf(gelu_f(a[j] + bb[j]));
  *(uint4*)(t2b + (size_t)tok * HIDDIM + c) = *(uint4*)o;
}

// ---------- launch ----------
extern "C" void kernel_launch(void* const* d_in, const int* in_sizes, int n_in,
                              void* d_out, int out_size, void* d_ws, size_t ws_size,
                              hipStream_t stream) {
  (void)in_sizes; (void)n_in; (void)out_size; (void)ws_size;
  const float* x     = (const float*)d_in[0];
  const float* n1g   = (const float*)d_in[1];
  const float* n1b   = (const float*)d_in[2];
  const float* wq    = (const float*)d_in[3];
  const float* bq    = (const float*)d_in[4];
  const float* wv    = (const float*)d_in[5];
  const float* bv    = (const float*)d_in[6];
  const float* rpb   = (const float*)d_in[7];
  const float* wproj = (const float*)d_in[8];
  const float* bproj = (const float*)d_in[9];
  const float* n2g   = (const float*)d_in[10];
  const float* n2b   = (const float*)d_in[11];
  const float* w1    = (const float*)d_in[12];
  const float* b1    = (const float*)d_in[13];
  const float* dwk   = (const float*)d_in[14];
  const float* dwb   = (const float*)d_in[15];
  const float* w2    = (const float*)d_in[16];
  const float* b2    = (const float*)d_in[17];
  const int*   pHo   = (const int*)d_in[18];
  const int*   pWo   = (const int*)d_in[19];
  float* out = (float*)d_out;

  char* wsb = (char*)d_ws;
  unsigned short* r0     = (unsigned short*)wsb;
  unsigned short* wqt    = (unsigned short*)(wsb + 67108864ull);
  unsigned short* wvt    = (unsigned short*)(wsb + 67108864ull + 131072ull);
  unsigned short* wprojt = (unsigned short*)(wsb + 67108864ull + 262144ull);
  unsigned short* w1t    = (unsigned short*)(wsb + 67108864ull + 393216ull);
  unsigned short* w2t    = (unsigned short*)(wsb + 67108864ull + 917504ull);
  unsigned short* t1b    = (unsigned short*)(wsb + 68550656ull);
  unsigned short* t2b    = (unsigned short*)(wsb + 68550656ull + 25690112ull);
  unsigned short* vb     = (unsigned short*)d_out;
  unsigned short* qb     = (unsigned short*)((char*)d_out + 67108864ull);

  // 0. weight convert + transpose (f32 [K,N] -> bf16 [N,K]); wqt/wvt adjacent
  //    so they form one contiguous [512][256] Bt for the fused QV GEMM.
  wconv_kernel<<<dim3(8, 8),  256, 0, stream>>>(wq,    wqt,    CDIM, CDIM);
  wconv_kernel<<<dim3(8, 8),  256, 0, stream>>>(wv,    wvt,    CDIM, CDIM);
  wconv_kernel<<<dim3(8, 8),  256, 0, stream>>>(wproj, wprojt, CDIM, CDIM);
  wconv_kernel<<<dim3(8, 32), 256, 0, stream>>>(w1,    w1t,    CDIM, HIDDIM);
  wconv_kernel<<<dim3(32, 8), 256, 0, stream>>>(w2,    w2t,    HIDDIM, CDIM);

  // 1. LN1: x -> xn (r0)
  ln_kernel<<<32768, 256, 0, stream>>>(x, n1g, n1b, r0);
  // 2. fused q+v projection -> permuted window-major layouts in d_out halves
  mgemm<0, 4><<<dim3(1024, 4), 256, 0, stream>>>(
      r0, wqt, bq, bv, nullptr, qb, vb, CDIM, CDIM, pHo, pWo);
  // 3. window attention (k = q) -> yattn (r0, TOKEN order)
  attn_kernel<<<dim3(2048), 256, 0, stream>>>(qb, vb, rpb, pHo, pWo, r0);
  // 4. xattn = x + yattn@wproj + bproj -> d_out f32 (all linear)
  mgemm<1, 0><<<dim3(1024, 2), 256, 0, stream>>>(
      r0, wprojt, bproj, nullptr, x, out, nullptr, CDIM, CDIM, pHo, pWo);
  // 5. LN2: d_out -> xn2 (r0)
  ln_kernel<<<32768, 256, 0, stream>>>(out, n2g, n2b, r0);
  // 6-8. LeFF over row bands
  for (int bi = 0; bi < BATCH; ++bi) {
    for (int hr0 = 0; hr0 < H_IMG; ) {
      const int br = (H_IMG - hr0 >= 96) ? 96 : (H_IMG - hr0);
      const int r_start = (hr0 > 0) ? hr0 - 1 : 0;
      const int r_end = (hr0 + br <= H_IMG - 1) ? hr0 + br : H_IMG - 1;
      const int nrows = r_end - r_start + 1;
      const unsigned short* Aff1 = r0 + ((size_t)bi * LTOK + (size_t)r_start * W_IMG) * CDIM;
      unsigned short* t1dst = t1b + (size_t)(r_start - hr0 + 1) * W_IMG * HIDDIM;
      mgemm<2, 0><<<dim3(nrows, 8), 256, 0, stream>>>(
          Aff1, w1t, b1, nullptr, nullptr, t1dst, nullptr, CDIM, HIDDIM, pHo, pWo);
      dwconv_kernel<<<dim3(br * 16, 4), 256, 0, stream>>>(t1b, dwk, dwb, t2b, hr0, br);
      const size_t btok = (size_t)bi * LTOK + (size_t)hr0 * W_IMG;
      mgemm<1, 0><<<dim3(br, 2), 256, 0, stream>>>(
          t2b, w2t, b2, nullptr, out + btok * CDIM, out + btok * CDIM, nullptr,
          HIDDIM, CDIM, pHo, pWo);
      hr0 += br;
    }
  }
}

// Round 4
// 1594.786 us; speedup vs baseline: 1.0382x; 1.0307x over previous
//
#include <hip/hip_runtime.h>
#include <stdint.h>
#include <math.h>

// Problem constants (fixed by setup_inputs)
#define H_IMG 256
#define W_IMG 128
#define LTOK  32768
#define BATCH 4
#define CDIM  256
#define HIDDIM 1024
#define NHEAD 8
#define HD    32
#define MROWS 131072   // B * L

typedef __attribute__((ext_vector_type(8))) short short8;
typedef __attribute__((ext_vector_type(4))) float f32x4;

// ---------- helpers ----------
__device__ __forceinline__ float bf2f(unsigned u) {
  union { unsigned u; float f; } c; c.u = u << 16; return c.f;
}
__device__ __forceinline__ unsigned short f2bf(float f) {
  union { float f; unsigned u; } c; c.f = f;
  unsigned r = c.u + 0x7fffu + ((c.u >> 16) & 1u);  // RNE
  return (unsigned short)(r >> 16);
}
__device__ __forceinline__ void unpack8(uint4 t, float* dst) {
  dst[0] = bf2f(t.x & 0xffffu); dst[1] = bf2f(t.x >> 16);
  dst[2] = bf2f(t.y & 0xffffu); dst[3] = bf2f(t.y >> 16);
  dst[4] = bf2f(t.z & 0xffffu); dst[5] = bf2f(t.z >> 16);
  dst[6] = bf2f(t.w & 0xffffu); dst[7] = bf2f(t.w >> 16);
}
__device__ __forceinline__ float gelu_f(float x) {
  return 0.5f * x * (1.0f + erff(x * 0.70710678118654752f));
}
__device__ __forceinline__ void gload_lds16(const void* g, void* l) {
  __builtin_amdgcn_global_load_lds(
      (const __attribute__((address_space(1))) unsigned int*)g,
      (__attribute__((address_space(3))) unsigned int*)l, 16, 0, 0);
}

// ---------- weight convert: f32 [K,N] -> bf16 [N,K] (transpose) ----------
__global__ __launch_bounds__(256) void wconv_kernel(
    const float* __restrict__ w, unsigned short* __restrict__ wt, int K, int N) {
  __shared__ float t[32][33];
  const int k0 = blockIdx.x * 32, n0 = blockIdx.y * 32;
  const int tx = threadIdx.x & 31, ty = threadIdx.x >> 5;
#pragma unroll
  for (int i = 0; i < 4; ++i)
    t[ty + 8 * i][tx] = w[(size_t)(k0 + ty + 8 * i) * N + n0 + tx];
  __syncthreads();
#pragma unroll
  for (int i = 0; i < 4; ++i)
    wt[(size_t)(n0 + ty + 8 * i) * K + k0 + tx] = f2bf(t[tx][ty + 8 * i]);
}

// ---------- LayerNorm (fp32 in -> bf16 out), one wave per row of C=256 ----------
__global__ __launch_bounds__(256) void ln_kernel(
    const float* __restrict__ x, const float* __restrict__ g,
    const float* __restrict__ b, unsigned short* __restrict__ out) {
  const int wave = threadIdx.x >> 6;
  const int lane = threadIdx.x & 63;
  const size_t row = (size_t)blockIdx.x * 4 + wave;
  float4 f = ((const float4*)(x + row * CDIM))[lane];
  float s  = f.x + f.y + f.z + f.w;
  float sq = f.x*f.x + f.y*f.y + f.z*f.z + f.w*f.w;
#pragma unroll
  for (int o = 32; o > 0; o >>= 1) { s += __shfl_down(s, o); sq += __shfl_down(sq, o); }
  s = __shfl(s, 0); sq = __shfl(sq, 0);
  const float mu = s * (1.0f / CDIM);
  const float var = sq * (1.0f / CDIM) - mu * mu;
  const float rstd = rsqrtf(var + 1e-5f);
  float4 gg = ((const float4*)g)[lane];
  float4 bb = ((const float4*)b)[lane];
  unsigned short o4[4];
  o4[0] = f2bf((f.x - mu) * rstd * gg.x + bb.x);
  o4[1] = f2bf((f.y - mu) * rstd * gg.y + bb.y);
  o4[2] = f2bf((f.z - mu) * rstd * gg.z + bb.z);
  o4[3] = f2bf((f.w - mu) * rstd * gg.w + bb.w);
  *(uint2*)(out + row * CDIM + lane * 4) = *(uint2*)o4;
}

// ---------- MFMA GEMM: out[M,:] = A[M,K](bf16) @ Bt[N,K](bf16)^T + bias ----------
// Depth-2 pipelined k-loop: 3 LDS buffers, STAGE(t+2) issued before compute(t),
// raw s_barrier + counted vmcnt(8) steady-state -> 2 k-steps of HBM latency
// hide under MFMA. LDS 48KB; occupancy is register-capped at 3 blocks/CU so
// the extra buffer costs nothing.
// EPI 0: bf16 = acc+bias   EPI 1: f32 = acc+bias+res   EPI 2: bf16 = gelu(acc+bias)
// PERM 0: linear, out idx = m*ldc+n
// PERM 4: fused q/v projection. Bt has 512 rows ([wq cols; wv cols]); output is
//   ONE buffer [b][win][head16][tok64][32] (head16 = n>>5: 0..7 = q, 8..15 = v);
//   roll+window gather folded into write addresses. All stores are 32B segments.
template<int EPI, int PERM>
__global__ __launch_bounds__(256) void mgemm(
    const unsigned short* __restrict__ A, const unsigned short* __restrict__ Bt,
    const float* __restrict__ bias, const float* __restrict__ bias2,
    const float* __restrict__ res, void* __restrict__ outp,
    int K, int ldc, const int* __restrict__ pHo, const int* __restrict__ pWo) {
  __shared__ unsigned short As[3][128][32];
  __shared__ unsigned short Bs[3][128][32];
  const int tid = threadIdx.x;
  const int w = tid >> 6, lane = tid & 63;
  const int m0 = blockIdx.x * 128, n0 = blockIdx.y * 128;
  const int wm = (w & 1) * 64, wn = (w >> 1) * 64;
  const int srow = lane >> 2;                 // 0..15 within a 16-row chunk
  const int csrc = (lane & 3) ^ (srow & 3);   // swizzled source 16B-chunk
  f32x4 acc[4][4];
#pragma unroll
  for (int mi = 0; mi < 4; ++mi)
#pragma unroll
    for (int ni = 0; ni < 4; ++ni)
#pragma unroll
      for (int r = 0; r < 4; ++r) acc[mi][ni][r] = 0.0f;

  const int kg = lane >> 4, ml = lane & 15;
  const int nt = K >> 5;

  auto STAGE = [&](int kk, int buf) {
#pragma unroll
    for (int i = 0; i < 2; ++i) {
      const int rl = w * 32 + i * 16 + srow;       // local row 0..127
      gload_lds16(A + (size_t)(m0 + rl) * K + kk + csrc * 8, &As[buf][w * 32 + i * 16][0]);
      gload_lds16(Bt + (size_t)(n0 + rl) * K + kk + csrc * 8, &Bs[buf][w * 32 + i * 16][0]);
    }
  };

  STAGE(0, 0);
  if (nt > 1) STAGE(32, 1);
  for (int t = 0; t < nt; ++t) {
    const int cur = t % 3;
    if (t + 2 < nt) {
      STAGE((t + 2) << 5, (t + 2) % 3);
      asm volatile("s_waitcnt vmcnt(8)" ::: "memory");   // t's 4 loads retired
    } else if (t + 1 < nt) {
      asm volatile("s_waitcnt vmcnt(4)" ::: "memory");
    } else {
      asm volatile("s_waitcnt vmcnt(0)" ::: "memory");
    }
    __builtin_amdgcn_s_barrier();
    __builtin_amdgcn_sched_barrier(0);
    short8 af[4], bg[4];
#pragma unroll
    for (int mi = 0; mi < 4; ++mi) {
      const int r = wm + mi * 16 + ml;
      af[mi] = *(const short8*)&As[cur][r][(kg ^ (r & 3)) * 8];
    }
#pragma unroll
    for (int ni = 0; ni < 4; ++ni) {
      const int r = wn + ni * 16 + ml;
      bg[ni] = *(const short8*)&Bs[cur][r][(kg ^ (r & 3)) * 8];
    }
#pragma unroll
    for (int mi = 0; mi < 4; ++mi)
#pragma unroll
      for (int ni = 0; ni < 4; ++ni)
        acc[mi][ni] = __builtin_amdgcn_mfma_f32_16x16x32_bf16(af[mi], bg[ni], acc[mi][ni], 0, 0, 0);
    __builtin_amdgcn_sched_barrier(0);
    __builtin_amdgcn_s_barrier();
  }

  // epilogue: C/D layout col=lane&15, row=(lane>>4)*4+r
  if constexpr (PERM == 4) {
    const int Ho = pHo[0], Wo = pWo[0];
    size_t rbase[4][4];
#pragma unroll
    for (int mi = 0; mi < 4; ++mi) {
#pragma unroll
      for (int r = 0; r < 4; ++r) {
        const int m = m0 + wm + mi * 16 + kg * 4 + r;
        const int bimg = m >> 15, l = m & 32767;
        int hr = (l >> 7) - Ho; if (hr < 0) hr += H_IMG;
        int wr = (l & 127) - Wo; if (wr < 0) wr += W_IMG;
        const int win = (hr >> 3) * 16 + (wr >> 3);
        const int t64 = (hr & 7) * 8 + (wr & 7);
        rbase[mi][r] = (size_t)(bimg * 512 + win) * 32768 + t64 * 32;
      }
    }
    unsigned short* dst = (unsigned short*)outp;
#pragma unroll
    for (int ni = 0; ni < 4; ++ni) {
      const int nn = n0 + wn + ni * 16 + ml;   // 0..511
      const float bn = (nn < 256) ? bias[nn] : bias2[nn - 256];
      const size_t noff = (size_t)(nn >> 5) * 2048 + (nn & 31);
#pragma unroll
      for (int mi = 0; mi < 4; ++mi)
#pragma unroll
        for (int r = 0; r < 4; ++r)
          dst[rbase[mi][r] + noff] = f2bf(acc[mi][ni][r] + bn);
    }
  } else {
#pragma unroll
    for (int ni = 0; ni < 4; ++ni) {
      const int n = n0 + wn + ni * 16 + ml;
      const float bn = bias[n];
#pragma unroll
      for (int mi = 0; mi < 4; ++mi) {
#pragma unroll
        for (int r = 0; r < 4; ++r) {
          const int m = m0 + wm + mi * 16 + kg * 4 + r;
          const size_t idx = (size_t)m * ldc + n;
          float val = acc[mi][ni][r] + bn;
          if (EPI == 1) {
            ((float*)outp)[idx] = val + res[idx];
          } else if (EPI == 2) {
            ((unsigned short*)outp)[idx] = f2bf(gelu_f(val));
          } else {
            ((unsigned short*)outp)[idx] = f2bf(val);
          }
        }
      }
    }
  }
}

// ---------- Window attention via MFMA (k = q shared) ----------
// qv: [b][512 win][16 head][64 tok][32]  (heads 0..7 = q, 8..15 = v)
// Q/K fragments load direct from global (coalesced); V loaded per-token and
// transposed to [32 d][72-pitch tok] via wave-private LDS (row-uniform b16
// writes, conflict-free), issued BEFORE QK^T so HBM latency hides under MFMA.
// OUTPUT written at un-permuted TOKEN addresses so wproj is fully linear.
// One block = one window (4 waves); wave w does heads {w, w+4}. Max-free
// softmax (scores bounded; mask -100 underflows in expf); 1/sum folded into O
// after PV. P [64][64] overlays vt after V fragments are in regs.
// No __syncthreads in the hot loop.
__global__ __launch_bounds__(256, 3) void attn_kernel(
    const unsigned short* __restrict__ qv, const float* __restrict__ rpb,
    const int* __restrict__ pHo, const int* __restrict__ pWo,
    unsigned short* __restrict__ yout) {
  __shared__ unsigned short Pb[4][4096];   // per-wave 8KB: vt[32][72] -> P[64][64] -> Ost[64][40]
  __shared__ float bias_w[4][228];
  __shared__ int reg_s[64];
  const int tid = threadIdx.x;
  const int w = tid >> 6, lane = tid & 63;
  const int g = lane >> 4, c = lane & 15;
  const int wb = blockIdx.x;         // b*512 + wh*16 + ww
  const int b = wb >> 9, wloc = wb & 511;
  const int wh = wloc >> 4, ww = wloc & 15;
  const int Ho = pHo[0], Wo = pWo[0];
  const bool edge = (wh == (H_IMG / 8 - 1)) || (ww == (W_IMG / 8 - 1));
  if (w == 0) {
    const int dy = lane >> 3, dx = lane & 7;
    const int hr = wh * 8 + dy, wr = ww * 8 + dx;
    const int rh = (hr < H_IMG - 8) ? 0 : ((hr < H_IMG - Ho) ? 1 : 2);
    const int rw = (wr < W_IMG - 8) ? 0 : ((wr < W_IMG - Wo) ? 1 : 2);
    reg_s[lane] = rh * 3 + rw;
  }
  __syncthreads();

  const float scale = 0.17677669529663687f;  // 32^-0.5
  const int dxk = c & 7, dyk0 = c >> 3;
  const int base_l = 112 - dyk0 * 15 - dxk;  // rel = Aq + base_l - 30*nj
  const size_t hbase = (size_t)(b * 512 + wloc) * 32768;
  // un-permuted token address for this lane's output row
  const int dy2 = lane >> 3, dx2 = lane & 7;
  int h2 = wh * 8 + dy2 + Ho; if (h2 >= H_IMG) h2 -= H_IMG;
  int w2_ = ww * 8 + dx2 + Wo; if (w2_ >= W_IMG) w2_ -= W_IMG;
  const size_t otok = (size_t)b * LTOK + (size_t)h2 * W_IMG + w2_;

  for (int p2 = 0; p2 < 2; ++p2) {
    const int hh = w + 4 * p2;
    const unsigned short* qh = qv + hbase + hh * 2048;
    const unsigned short* vh = qv + hbase + (8 + hh) * 2048;
    // ---- V token-row loads issued first (latency hides under QK^T) ----
    const uint4* vp = (const uint4*)(vh + lane * 32);
    uint4 a0 = vp[0], a1 = vp[1], a2 = vp[2], a3 = vp[3];
    // bias slice (wave-private)
#pragma unroll
    for (int i = 0; i < 4; ++i) {
      const int idx = lane + 64 * i;
      if (idx < 225) bias_w[w][idx] = rpb[idx * 8 + hh];
    }
    // ---- Q fragments direct from global (coalesced 16B/lane) ----
    short8 q4[4];
#pragma unroll
    for (int mi = 0; mi < 4; ++mi)
      q4[mi] = *(const short8*)(qh + (16 * mi + c) * 32 + g * 8);
    // ---- QK^T: S[q-tile mi][k-tile nj] (same fragments serve A and B) ----
    f32x4 acc[4][4];
#pragma unroll
    for (int mi = 0; mi < 4; ++mi)
#pragma unroll
      for (int nj = 0; nj < 4; ++nj)
#pragma unroll
        for (int r = 0; r < 4; ++r) acc[mi][nj][r] = 0.0f;
#pragma unroll
    for (int mi = 0; mi < 4; ++mi)
#pragma unroll
      for (int nj = 0; nj < 4; ++nj)
        acc[mi][nj] = __builtin_amdgcn_mfma_f32_16x16x32_bf16(q4[mi], q4[nj], acc[mi][nj], 0, 0, 0);
    // ---- V transpose into wave-private LDS vt[32][72] ----
    unsigned short* vt = &Pb[w][0];
    {
      unsigned tmp[16] = {a0.x,a0.y,a0.z,a0.w,a1.x,a1.y,a1.z,a1.w,
                          a2.x,a2.y,a2.z,a2.w,a3.x,a3.y,a3.z,a3.w};
#pragma unroll
      for (int d2 = 0; d2 < 16; ++d2) {
        vt[(2 * d2) * 72 + lane]     = (unsigned short)(tmp[d2] & 0xffffu);
        vt[(2 * d2 + 1) * 72 + lane] = (unsigned short)(tmp[d2] >> 16);
      }
    }
    short8 vf[2][2];
#pragma unroll
    for (int s2 = 0; s2 < 2; ++s2)
#pragma unroll
      for (int n2 = 0; n2 < 2; ++n2)
        vf[s2][n2] = *(const short8*)&vt[(16 * n2 + c) * 72 + 32 * s2 + 8 * g];
    int regk[4];
    if (edge) {
#pragma unroll
      for (int nj = 0; nj < 4; ++nj) regk[nj] = reg_s[16 * nj + c];
    }
    // ---- max-free softmax per row (C-layout row q=16mi+4g+r, col kt=16nj+c) ----
    // P writes overlay vt (V fragments already in registers).
    unsigned short* Pp = &Pb[w][0];
    float ivr[4][4];
#pragma unroll
    for (int mi = 0; mi < 4; ++mi) {
#pragma unroll
      for (int r = 0; r < 4; ++r) {
        const int qq = 16 * mi + 4 * g + r;
        const int rb = (qq >> 3) * 15 + (qq & 7) + base_l;
        float sv[4];
#pragma unroll
        for (int nj = 0; nj < 4; ++nj)
          sv[nj] = acc[mi][nj][r] * scale + bias_w[w][rb - 30 * nj];
        if (edge) {
          const int regq = reg_s[qq];
#pragma unroll
          for (int nj = 0; nj < 4; ++nj)
            if (regq != regk[nj]) sv[nj] -= 100.0f;
        }
        float e0 = __expf(sv[0]), e1 = __expf(sv[1]);
        float e2 = __expf(sv[2]), e3 = __expf(sv[3]);
        float sm = e0 + e1 + e2 + e3;
        sm += __shfl_xor(sm, 1);
        sm += __shfl_xor(sm, 2);
        sm += __shfl_xor(sm, 4);
        sm += __shfl_xor(sm, 8);
        ivr[mi][r] = __builtin_amdgcn_rcpf(sm);
        const int rowoff = qq * 64, sw = qq & 7;
        Pp[rowoff + ((dyk0 ^ sw) * 8)       + dxk] = f2bf(e0);
        Pp[rowoff + (((2 + dyk0) ^ sw) * 8) + dxk] = f2bf(e1);
        Pp[rowoff + (((4 + dyk0) ^ sw) * 8) + dxk] = f2bf(e2);
        Pp[rowoff + (((6 + dyk0) ^ sw) * 8) + dxk] = f2bf(e3);
      }
    }
    // ---- PV: O[q-tile mi][d-tile n2] over 2 K-steps ----
    f32x4 oacc[4][2];
#pragma unroll
    for (int mi = 0; mi < 4; ++mi)
#pragma unroll
      for (int n2 = 0; n2 < 2; ++n2)
#pragma unroll
        for (int r = 0; r < 4; ++r) oacc[mi][n2][r] = 0.0f;
#pragma unroll
    for (int s2 = 0; s2 < 2; ++s2) {
      short8 pa[4];
#pragma unroll
      for (int mi = 0; mi < 4; ++mi) {
        const int qq2 = 16 * mi + c;
        pa[mi] = *(const short8*)&Pp[qq2 * 64 + (((4 * s2 + g) ^ (qq2 & 7)) * 8)];
      }
#pragma unroll
      for (int mi = 0; mi < 4; ++mi)
#pragma unroll
        for (int n2 = 0; n2 < 2; ++n2)
          oacc[mi][n2] = __builtin_amdgcn_mfma_f32_16x16x32_bf16(pa[mi], vf[s2][n2], oacc[mi][n2], 0, 0, 0);
    }
    // ---- epilogue: normalize by 1/sum, restage O [64][40], coalesced write ----
    unsigned short* Ost = Pp;
#pragma unroll
    for (int mi = 0; mi < 4; ++mi)
#pragma unroll
      for (int n2 = 0; n2 < 2; ++n2)
#pragma unroll
        for (int r = 0; r < 4; ++r)
          Ost[(16 * mi + 4 * g + r) * 40 + 16 * n2 + c] = f2bf(oacc[mi][n2][r] * ivr[mi][r]);
    uint4* op = (uint4*)(yout + otok * CDIM + hh * 32);
#pragma unroll
    for (int u = 0; u < 4; ++u)
      op[u] = *(const uint4*)&Ost[lane * 40 + u * 8];
  }
}

// ---------- Depthwise 3x3 conv on a row band (full 1024 ch) + GELU ----------
// 8 channels/thread (uint4 loads, 16B stores).
__global__ __launch_bounds__(256) void dwconv_kernel(
    const unsigned short* __restrict__ t1b, const float* __restrict__ k9,
    const float* __restrict__ bias, unsigned short* __restrict__ t2b,
    int hr0, int band_rows) {
  const int c = blockIdx.y * 256 + (threadIdx.x & 31) * 8;
  const int tok = blockIdx.x * 8 + (threadIdx.x >> 5);   // 0..band_rows*128-1
  const int h = hr0 + (tok >> 7), wcol = tok & 127;
  float wreg[8][9];
#pragma unroll
  for (int j = 0; j < 8; ++j)
#pragma unroll
    for (int tp = 0; tp < 9; ++tp) wreg[j][tp] = k9[(c + j) * 9 + tp];
  float bb[8];
#pragma unroll
  for (int j = 0; j < 8; ++j) bb[j] = bias[c + j];
  float a[8] = {};
#pragma unroll
  for (int ky = 0; ky < 3; ++ky) {
    const int hy = h + ky - 1;
    if ((unsigned)hy >= (unsigned)H_IMG) continue;
    const int brow = (tok >> 7) + ky;   // buffer row
#pragma unroll
    for (int kx = 0; kx < 3; ++kx) {
      const int wx = wcol + kx - 1;
      if ((unsigned)wx >= (unsigned)W_IMG) continue;
      const uint4 tv = *(const uint4*)(
          t1b + ((size_t)(brow * 128 + wx)) * HIDDIM + c);
      float f8[8];
      unpack8(tv, f8);
      const int tp = ky * 3 + kx;
#pragma unroll
      for (int j = 0; j < 8; ++j) a[j] += f8[j] * wreg[j][tp];
    }
  }
  unsigned short o[8];
#pragma unroll
  for (int j = 0; j < 8; ++j) o[j] = f2bf(gelu_f(a[j] + bb[j]));
  *(uint4*)(t2b + (size_t)tok * HIDDIM + c) = *(uint4*)o;
}

// ---------- launch ----------
extern "C" void kernel_launch(void* const* d_in, const int* in_sizes, int n_in,
                              void* d_out, int out_size, void* d_ws, size_t ws_size,
                              hipStream_t stream) {
  (void)in_sizes; (void)n_in; (void)out_size; (void)ws_size;
  const float* x     = (const float*)d_in[0];
  const float* n1g   = (const float*)d_in[1];
  const float* n1b   = (const float*)d_in[2];
  const float* wq    = (const float*)d_in[3];
  const float* bq    = (const float*)d_in[4];
  const float* wv    = (const float*)d_in[5];
  const float* bv    = (const float*)d_in[6];
  const float* rpb   = (const float*)d_in[7];
  const float* wproj = (const float*)d_in[8];
  const float* bproj = (const float*)d_in[9];
  const float* n2g   = (const float*)d_in[10];
  const float* n2b   = (const float*)d_in[11];
  const float* w1    = (const float*)d_in[12];
  const float* b1    = (const float*)d_in[13];
  const float* dwk   = (const float*)d_in[14];
  const float* dwb   = (const float*)d_in[15];
  const float* w2    = (const float*)d_in[16];
  const float* b2    = (const float*)d_in[17];
  const int*   pHo   = (const int*)d_in[18];
  const int*   pWo   = (const int*)d_in[19];
  float* out = (float*)d_out;

  char* wsb = (char*)d_ws;
  unsigned short* r0     = (unsigned short*)wsb;
  unsigned short* wqt    = (unsigned short*)(wsb + 67108864ull);
  unsigned short* wvt    = (unsigned short*)(wsb + 67108864ull + 131072ull);
  unsigned short* wprojt = (unsigned short*)(wsb + 67108864ull + 262144ull);
  unsigned short* w1t    = (unsigned short*)(wsb + 67108864ull + 393216ull);
  unsigned short* w2t    = (unsigned short*)(wsb + 67108864ull + 917504ull);
  unsigned short* t1b    = (unsigned short*)(wsb + 68550656ull);
  unsigned short* t2b    = (unsigned short*)(wsb + 68550656ull + 25690112ull);
  unsigned short* qvb    = (unsigned short*)d_out;   // [b][win][16 head][64][32] = 128 MB

  // 0. weight convert + transpose (f32 [K,N] -> bf16 [N,K]); wqt/wvt adjacent
  //    so they form one contiguous [512][256] Bt for the fused QV GEMM.
  wconv_kernel<<<dim3(8, 8),  256, 0, stream>>>(wq,    wqt,    CDIM, CDIM);
  wconv_kernel<<<dim3(8, 8),  256, 0, stream>>>(wv,    wvt,    CDIM, CDIM);
  wconv_kernel<<<dim3(8, 8),  256, 0, stream>>>(wproj, wprojt, CDIM, CDIM);
  wconv_kernel<<<dim3(8, 32), 256, 0, stream>>>(w1,    w1t,    CDIM, HIDDIM);
  wconv_kernel<<<dim3(32, 8), 256, 0, stream>>>(w2,    w2t,    HIDDIM, CDIM);

  // 1. LN1: x -> xn (r0)
  ln_kernel<<<32768, 256, 0, stream>>>(x, n1g, n1b, r0);
  // 2. fused q+v projection -> one window-major [b][win][head16][64][32] buffer
  mgemm<0, 4><<<dim3(1024, 4), 256, 0, stream>>>(
      r0, wqt, bq, bv, nullptr, qvb, CDIM, CDIM, pHo, pWo);
  // 3. window attention (k = q) -> yattn (r0, TOKEN order)
  attn_kernel<<<dim3(2048), 256, 0, stream>>>(qvb, rpb, pHo, pWo, r0);
  // 4. xattn = x + yattn@wproj + bproj -> d_out f32 (all linear; qv dead)
  mgemm<1, 0><<<dim3(1024, 2), 256, 0, stream>>>(
      r0, wprojt, bproj, nullptr, x, out, CDIM, CDIM, pHo, pWo);
  // 5. LN2: d_out -> xn2 (r0)
  ln_kernel<<<32768, 256, 0, stream>>>(out, n2g, n2b, r0);
  // 6-8. LeFF over row bands
  for (int bi = 0; bi < BATCH; ++bi) {
    for (int hr0 = 0; hr0 < H_IMG; ) {
      const int br = (H_IMG - hr0 >= 96) ? 96 : (H_IMG - hr0);
      const int r_start = (hr0 > 0) ? hr0 - 1 : 0;
      const int r_end = (hr0 + br <= H_IMG - 1) ? hr0 + br : H_IMG - 1;
      const int nrows = r_end - r_start + 1;
      const unsigned short* Aff1 = r0 + ((size_t)bi * LTOK + (size_t)r_start * W_IMG) * CDIM;
      unsigned short* t1dst = t1b + (size_t)(r_start - hr0 + 1) * W_IMG * HIDDIM;
      mgemm<2, 0><<<dim3(nrows, 8), 256, 0, stream>>>(
          Aff1, w1t, b1, nullptr, nullptr, t1dst, CDIM, HIDDIM, pHo, pWo);
      dwconv_kernel<<<dim3(br * 16, 4), 256, 0, stream>>>(t1b, dwk, dwb, t2b, hr0, br);
      const size_t btok = (size_t)bi * LTOK + (size_t)hr0 * W_IMG;
      mgemm<1, 0><<<dim3(br, 2), 256, 0, stream>>>(
          t2b, w2t, b2, nullptr, out + btok * CDIM, out + btok * CDIM,
          HIDDIM, CDIM, pHo, pWo);
      hr0 += br;
    }
  }
}